// Round 6
// baseline (182.299 us; speedup 1.0000x reference)
//
#include <hip/hip_runtime.h>
#include <hip/hip_bf16.h>

#define DIM    286
#define DIMP   288
#define NZTOT  55296     // 48*24*48
#define NBATCH 256
#define NB_    24
#define NA_    48
#define ZC     32        // z per tile
#define NTILES 1728      // NZTOT/ZC
#define NCHUNK 192       // z-chunk workgroups (grid.x)
#define TILES_PER_WG 9   // NTILES/NCHUNK
#define S_CONST 16.911534525287763f
#define INV_S   0.05913123959890826f
#define ACT_CST 1.5927f  // normalize2mom const for tanh

typedef short bf16x8 __attribute__((ext_vector_type(8)));
typedef float f32x4  __attribute__((ext_vector_type(4)));

// ws layout (bytes)
#define WS_FBF  0u
#define WS_DBF  147456u                      // Fbf: 256*288*2
#define WS_DT   (WS_DBF + 31850496u)         // Dbf: 55296*288*2
#define WS_PART (WS_DT + 31850496u)          // Dt2: 1728 tiles * 288 * 32 * 2
                                             // part: 192*256*288*4 = 56623104

typedef const __attribute__((address_space(1))) char GA;
typedef __attribute__((address_space(3))) char LA;
__device__ __forceinline__ void gload_lds16(const void* g, void* l) {
    __builtin_amdgcn_global_load_lds((GA*)g, (LA*)l, 16, 0, 0);
}

// ---------- fused prep: blocks [0,1728) do D->Dbf/Dt2; blocks [1728,2016) do F->Fbf
// fp32 staging in two 16-z half-slabs: LDS 19.5KB -> ~8 blocks/CU, exact R4 numerics.
__global__ void k_prep(const float* __restrict__ F, const float* __restrict__ D,
                       const float* __restrict__ qw,
                       __hip_bfloat16* __restrict__ Fbf,
                       __hip_bfloat16* __restrict__ Dbf, __hip_bfloat16* __restrict__ Dt2) {
    __shared__ float T[16][304];             // 1216B rows (16-aligned); 304%32=16
    __shared__ float qs[24];
    int t = threadIdx.x;
    int bid = blockIdx.x;
    if (bid >= NTILES) {
        // ---- prep_f: F -> bf16 [256][288], scaled by 1/s
        int o = (bid - NTILES) * 256 + t;    // 288*256 == 73728 exactly
        int row = o / DIMP, col = o % DIMP;
        float v = (col < DIM) ? F[row * DIM + col] * INV_S : 0.f;
        Fbf[o] = __float2bfloat16(v);
        return;
    }
    int z0 = bid * 32;
    if (t < 24) qs[t] = qw[t] * S_CONST;
    #pragma unroll 1
    for (int h = 0; h < 2; ++h) {
        int zh = z0 + h * 16;
        // phase 1: coalesced float4 loads (16*286 = 4576 floats = 1144 float4)
        const float4* Df = (const float4*)(D + (size_t)zh * DIM);
        for (int k = 0; k < 5; ++k) {
            int idx = t + k * 256;
            if (idx < 1144) {
                float4 v = Df[idx];
                int e = idx * 4;
                int z = e / DIM, i = e % DIM;      // i always even
                T[z][i] = v.x; T[z][i + 1] = v.y;
                if (i == 284) { T[z + 1][0] = v.z; T[z + 1][1] = v.w; }  // i==284 => z even => z+1<=15
                else          { T[z][i + 2] = v.z; T[z][i + 3] = v.w; }
            }
        }
        if (t < 32) T[t >> 1][DIM + (t & 1)] = 0.f;   // zero pad cols 286..287
        __syncthreads();
        // phase 2: Dbf bf16x8 writes: 16 rows * 36 chunks = 576
        for (int s = 0; s < 3; ++s) {
            int idx = t + s * 256;
            if (idx < 576) {
                int r = idx / 36, c = idx % 36;
                float4 a = *(const float4*)(&T[r][c * 8]);
                float4 b = *(const float4*)(&T[r][c * 8 + 4]);
                __hip_bfloat16 o8[8];
                o8[0] = __float2bfloat16(a.x); o8[1] = __float2bfloat16(a.y);
                o8[2] = __float2bfloat16(a.z); o8[3] = __float2bfloat16(a.w);
                o8[4] = __float2bfloat16(b.x); o8[5] = __float2bfloat16(b.y);
                o8[6] = __float2bfloat16(b.z); o8[7] = __float2bfloat16(b.w);
                *(bf16x8*)(Dbf + (size_t)(zh + r) * DIMP + c * 8) = *(const bf16x8*)o8;
            }
        }
        // phase 3: Dt2[tz][i][zt] transpose for this half's 2 zc-groups: 288 i * 2 = 576
        for (int s = 0; s < 3; ++s) {
            int idx = t + s * 256;
            if (idx < 576) {
                int i = idx >> 1, zc2 = idx & 1;
                __hip_bfloat16 o8[8];
                #pragma unroll
                for (int j = 0; j < 8; ++j) {
                    int jj = (j + 2 * zc2) & 7;       // bank rotation
                    int zl = zc2 * 8 + jj;            // 0..15 within half
                    int y = ((zh + zl) / NA_) % NB_;
                    o8[jj] = __float2bfloat16(T[zl][i] * qs[y]);
                }
                *(bf16x8*)(Dt2 + ((size_t)bid * DIMP + i) * ZC + (h * 2 + zc2) * 8) = *(const bf16x8*)o8;
            }
        }
        __syncthreads();   // T reused next half
    }
}

// ---------- fused main: double-buffered Ds/Dts, ONE barrier per tile.
// Explicit vmcnt(0) drain before the barrier guarantees the DMA has landed.
__launch_bounds__(256, 2)
__global__ void k_main(const __hip_bfloat16* __restrict__ Fbf,
                       const __hip_bfloat16* __restrict__ Dbf,
                       const __hip_bfloat16* __restrict__ Dt2,
                       float* __restrict__ part) {
    __shared__ __align__(16) __hip_bfloat16 Ds[2][32][288];    // [z][i]  2 x 18432 B
    __shared__ __align__(16) __hip_bfloat16 Dts[2][288][32];   // [i][z]  2 x 18432 B
    __shared__ __align__(16) __hip_bfloat16 Gs[4][16][40];     // per-wave act relayout

    int t = threadIdx.x;
    int wave = t >> 6, lane = t & 63, ln = lane & 15, q = lane >> 4;

    // cache F A-frags for this wave's 16 batch rows (9 K-steps of 32)
    bf16x8 fa[9];
    int row = blockIdx.y * 64 + wave * 16 + ln;
    const __hip_bfloat16* fp = Fbf + (size_t)row * DIMP + q * 8;
    #pragma unroll
    for (int ks = 0; ks < 9; ++ks) fa[ks] = *(const bf16x8*)(fp + ks * 32);

    f32x4 acc[18];
    #pragma unroll
    for (int n = 0; n < 18; ++n) acc[n] = (f32x4){0.f, 0.f, 0.f, 0.f};

    // wave-split staging: waves 0,1 -> Ds halves; waves 2,3 -> Dts halves; 9x1KB DMA each
    auto stage = [&](int tz, int b) {
        const char* src; char* dst;
        if (wave < 2) {
            src = (const char*)(Dbf + (size_t)tz * ZC * DIMP) + wave * 9216 + lane * 16;
            dst = ((char*)&Ds[b][0][0]) + wave * 9216;
        } else {
            src = (const char*)(Dt2 + (size_t)tz * DIMP * ZC) + (wave - 2) * 9216 + lane * 16;
            dst = ((char*)&Dts[b][0][0]) + (wave - 2) * 9216;
        }
        #pragma unroll
        for (int j = 0; j < 9; ++j)
            gload_lds16(src + j * 1024, dst + j * 1024);
    };

    stage(blockIdx.x, 0);   // prologue: tile 0 -> buf 0

    #pragma unroll 1
    for (int k = 0; k < TILES_PER_WG; ++k) {
        asm volatile("s_waitcnt vmcnt(0)" ::: "memory");   // DMA for buf k&1 landed
        __syncthreads();                                   // + buf (k+1)&1 free (all waves done)
        if (k + 1 < TILES_PER_WG) stage(blockIdx.x + (k + 1) * NCHUNK, (k + 1) & 1);
        int b = k & 1;
        // GEMM1: G[16 x 32] per wave, K=288
        f32x4 g0 = (f32x4){0.f,0.f,0.f,0.f}, g1 = (f32x4){0.f,0.f,0.f,0.f};
        #pragma unroll
        for (int ks = 0; ks < 9; ++ks) {
            bf16x8 b0 = *(const bf16x8*)(&Ds[b][ln][ks * 32 + q * 8]);
            bf16x8 b1 = *(const bf16x8*)(&Ds[b][16 + ln][ks * 32 + q * 8]);
            g0 = __builtin_amdgcn_mfma_f32_16x16x32_bf16(fa[ks], b0, g0, 0, 0, 0);
            g1 = __builtin_amdgcn_mfma_f32_16x16x32_bf16(fa[ks], b1, g1, 0, 0, 0);
        }
        // act = ACT_CST * tanh(g); relayout C-layout -> A-layout via per-wave LDS
        #pragma unroll
        for (int nf = 0; nf < 2; ++nf) {
            #pragma unroll
            for (int r = 0; r < 4; ++r) {
                float x = (nf == 0) ? g0[r] : g1[r];
                float a = fabsf(x);
                float e = __expf(-2.f * a);
                float th = (1.f - e) / (1.f + e);
                float v = copysignf(ACT_CST * th, x);
                Gs[wave][q * 4 + r][nf * 16 + ln] = __float2bfloat16(v);
            }
        }
        // GEMM2: Out[16 x 288] += G_act[16 x 32] * Dts (own-wave Gs only: no barrier needed)
        bf16x8 a2 = *(const bf16x8*)(&Gs[wave][ln][q * 8]);
        #pragma unroll
        for (int nf = 0; nf < 18; ++nf) {
            bf16x8 b2 = *(const bf16x8*)(&Dts[b][nf * 16 + ln][q * 8]);
            acc[nf] = __builtin_amdgcn_mfma_f32_16x16x32_bf16(a2, b2, acc[nf], 0, 0, 0);
        }
    }
    // epilogue: partial[zc][batch][288]
    float* pb = part + ((size_t)blockIdx.x * NBATCH + blockIdx.y * 64 + wave * 16) * DIMP;
    #pragma unroll
    for (int nf = 0; nf < 18; ++nf) {
        #pragma unroll
        for (int r = 0; r < 4; ++r) {
            pb[(size_t)(q * 4 + r) * DIMP + nf * 16 + ln] = acc[nf][r];
        }
    }
}

// ---------- reduce partials over the 192 z-chunks: 1152 blocks, 16-way zc split
__global__ void k_reduce(const float* __restrict__ part, float* __restrict__ out) {
    __shared__ float4 red[3][16];
    int t = threadIdx.x, wave = t >> 6, lane = t & 63;
    int j = lane & 15;                 // o4 slot within block
    int zg = wave * 4 + (lane >> 4);   // 0..15 zc-group
    int o4 = blockIdx.x * 16 + j;      // 1152*16 = 18432 slots
    int b = o4 / 72, c4 = o4 % 72;
    const float* p = part + (size_t)b * DIMP + c4 * 4;
    float4 s = make_float4(0.f, 0.f, 0.f, 0.f);
    #pragma unroll 4
    for (int ii = 0; ii < 12; ++ii) {
        float4 v = *(const float4*)(p + (size_t)(zg * 12 + ii) * NBATCH * DIMP);
        s.x += v.x; s.y += v.y; s.z += v.z; s.w += v.w;
    }
    // intra-wave: fold the 4 zc-groups (lane strides 16, 32)
    s.x += __shfl_down(s.x, 16); s.y += __shfl_down(s.y, 16);
    s.z += __shfl_down(s.z, 16); s.w += __shfl_down(s.w, 16);
    s.x += __shfl_down(s.x, 32); s.y += __shfl_down(s.y, 32);
    s.z += __shfl_down(s.z, 32); s.w += __shfl_down(s.w, 32);
    if (wave > 0 && lane < 16) red[wave - 1][lane] = s;
    __syncthreads();
    if (wave == 0 && lane < 16) {
        #pragma unroll
        for (int w = 0; w < 3; ++w) {
            float4 v = red[w][lane];
            s.x += v.x; s.y += v.y; s.z += v.z; s.w += v.w;
        }
        int i0 = c4 * 4;
        float sv[4] = {s.x, s.y, s.z, s.w};
        #pragma unroll
        for (int kk = 0; kk < 4; ++kk)
            if (i0 + kk < DIM) out[b * DIM + i0 + kk] = sv[kk];
    }
}

extern "C" void kernel_launch(void* const* d_in, const int* in_sizes, int n_in,
                              void* d_out, int out_size, void* d_ws, size_t ws_size,
                              hipStream_t stream) {
    const float* F  = (const float*)d_in[0];
    const float* D  = (const float*)d_in[1];
    const float* qw = (const float*)d_in[2];
    char* ws = (char*)d_ws;
    __hip_bfloat16* Fbf = (__hip_bfloat16*)(ws + WS_FBF);
    __hip_bfloat16* Dbf = (__hip_bfloat16*)(ws + WS_DBF);
    __hip_bfloat16* Dt2 = (__hip_bfloat16*)(ws + WS_DT);
    float* part = (float*)(ws + WS_PART);

    k_prep<<<NTILES + 288, 256, 0, stream>>>(F, D, qw, Fbf, Dbf, Dt2);
    k_main<<<dim3(NCHUNK, 4), 256, 0, stream>>>(Fbf, Dbf, Dt2, part);
    k_reduce<<<1152, 256, 0, stream>>>(part, (float*)d_out);
}

// Round 7
// 160.740 us; speedup vs baseline: 1.1341x; 1.1341x over previous
//
#include <hip/hip_runtime.h>
#include <hip/hip_bf16.h>

#define DIM    286
#define DIMP   288
#define NZTOT  55296     // 48*24*48
#define NBATCH 256
#define NB_    24
#define NA_    48
#define ZC     32        // z per tile
#define NTILES 1728      // NZTOT/ZC
#define NCHUNK 192       // z-chunk workgroups (grid.x)
#define TILES_PER_WG 9   // NTILES/NCHUNK
#define S_CONST 16.911534525287763f
#define INV_S   0.05913123959890826f
#define ACT_CST 1.5927f  // normalize2mom const for tanh

typedef short bf16x8 __attribute__((ext_vector_type(8)));
typedef float f32x4  __attribute__((ext_vector_type(4)));

// ws layout (bytes)
#define WS_FBF  0u
#define WS_DBF  147456u                      // Fbf: 256*288*2
#define WS_DT   (WS_DBF + 31850496u)         // Dbf: 55296*288*2
#define WS_PART (WS_DT + 31850496u)          // Dt2: 1728 tiles * 288 * 32 * 2
                                             // part: 192*256*288*4 = 56623104

typedef const __attribute__((address_space(1))) char GA;
typedef __attribute__((address_space(3))) char LA;
__device__ __forceinline__ void gload_lds16(const void* g, void* l) {
    __builtin_amdgcn_global_load_lds((GA*)g, (LA*)l, 16, 0, 0);
}

// ---------- fused prep: blocks [0,1728) do D->Dbf/Dt2; blocks [1728,2016) do F->Fbf
// One barrier. Dbf written straight from phase-1 registers (no LDS round-trip).
// T row stride 305 dwords (odd) -> transpose column reads are 2-way bank = free.
__global__ void k_prep(const float* __restrict__ F, const float* __restrict__ D,
                       const float* __restrict__ qw,
                       __hip_bfloat16* __restrict__ Fbf,
                       __hip_bfloat16* __restrict__ Dbf, __hip_bfloat16* __restrict__ Dt2) {
    __shared__ float T[32][305];
    __shared__ float qs[24];
    int t = threadIdx.x;
    int bid = blockIdx.x;
    if (bid >= NTILES) {
        // ---- prep_f: F -> bf16 [256][288], scaled by 1/s
        int o = (bid - NTILES) * 256 + t;    // 288*256 == 73728 exactly
        int row = o / DIMP, col = o % DIMP;
        float v = (col < DIM) ? F[row * DIM + col] * INV_S : 0.f;
        Fbf[o] = __float2bfloat16(v);
        return;
    }
    int z0 = bid * 32;
    if (t < 24) qs[t] = qw[t] * S_CONST;
    // phase 1: coalesced float4 loads (32*286 = 9152 floats = 2288 float4).
    // Store fp32 to T (for the transpose) AND bf16 direct to Dbf (two 4B stores, coalesced).
    const float4* Df = (const float4*)(D + (size_t)z0 * DIM);
    for (int k = 0; k < 9; ++k) {
        int idx = t + k * 256;
        if (idx < 2288) {
            float4 v = Df[idx];
            int e = idx * 4;
            int z = e / DIM, i = e % DIM;      // i always even
            __hip_bfloat162 lo, hi;
            lo.x = __float2bfloat16(v.x); lo.y = __float2bfloat16(v.y);
            hi.x = __float2bfloat16(v.z); hi.y = __float2bfloat16(v.w);
            T[z][i] = v.x; T[z][i + 1] = v.y;
            *(__hip_bfloat162*)(Dbf + (size_t)(z0 + z) * DIMP + i) = lo;
            if (i == 284) {   // i==284 => z even => z+1 <= 31
                T[z + 1][0] = v.z; T[z + 1][1] = v.w;
                *(__hip_bfloat162*)(Dbf + (size_t)(z0 + z + 1) * DIMP) = hi;
            } else {
                T[z][i + 2] = v.z; T[z][i + 3] = v.w;
                *(__hip_bfloat162*)(Dbf + (size_t)(z0 + z) * DIMP + i + 2) = hi;
            }
        }
    }
    if (t < 32) {   // zero K-pad cols 286..287 of Dbf
        __hip_bfloat162 zz; zz.x = __float2bfloat16(0.f); zz.y = zz.x;
        *(__hip_bfloat162*)(Dbf + (size_t)(z0 + t) * DIMP + DIM) = zz;
    }
    __syncthreads();
    // phase 2: Dt2[tz][i][z] transpose: 288 i * 4 zc = 1152 fully-contiguous 16B writes
    for (int s = 0; s < 5; ++s) {
        int idx = t + s * 256;
        if (idx < 1152) {
            int i = idx >> 2, zc = idx & 3;
            __hip_bfloat16 o8[8];
            #pragma unroll
            for (int j = 0; j < 8; ++j) {
                int zl = zc * 8 + j;
                int y = ((z0 + zl) / NA_) % NB_;
                o8[j] = __float2bfloat16(T[zl][i] * qs[y]);
            }
            *(bf16x8*)(Dt2 + ((size_t)bid * DIMP + i) * ZC + zc * 8) = *(const bf16x8*)o8;
        }
    }
}

// ---------- fused main: double-buffered Ds/Dts, ONE barrier per tile.
// Explicit vmcnt(0) drain before the barrier guarantees the DMA has landed.
__launch_bounds__(256, 2)
__global__ void k_main(const __hip_bfloat16* __restrict__ Fbf,
                       const __hip_bfloat16* __restrict__ Dbf,
                       const __hip_bfloat16* __restrict__ Dt2,
                       float* __restrict__ part) {
    __shared__ __align__(16) __hip_bfloat16 Ds[2][32][288];    // [z][i]  2 x 18432 B
    __shared__ __align__(16) __hip_bfloat16 Dts[2][288][32];   // [i][z]  2 x 18432 B
    __shared__ __align__(16) __hip_bfloat16 Gs[4][16][40];     // per-wave act relayout

    int t = threadIdx.x;
    int wave = t >> 6, lane = t & 63, ln = lane & 15, q = lane >> 4;

    // cache F A-frags for this wave's 16 batch rows (9 K-steps of 32)
    bf16x8 fa[9];
    int row = blockIdx.y * 64 + wave * 16 + ln;
    const __hip_bfloat16* fp = Fbf + (size_t)row * DIMP + q * 8;
    #pragma unroll
    for (int ks = 0; ks < 9; ++ks) fa[ks] = *(const bf16x8*)(fp + ks * 32);

    f32x4 acc[18];
    #pragma unroll
    for (int n = 0; n < 18; ++n) acc[n] = (f32x4){0.f, 0.f, 0.f, 0.f};

    // wave-split staging: waves 0,1 -> Ds halves; waves 2,3 -> Dts halves; 9x1KB DMA each
    auto stage = [&](int tz, int b) {
        const char* src; char* dst;
        if (wave < 2) {
            src = (const char*)(Dbf + (size_t)tz * ZC * DIMP) + wave * 9216 + lane * 16;
            dst = ((char*)&Ds[b][0][0]) + wave * 9216;
        } else {
            src = (const char*)(Dt2 + (size_t)tz * DIMP * ZC) + (wave - 2) * 9216 + lane * 16;
            dst = ((char*)&Dts[b][0][0]) + (wave - 2) * 9216;
        }
        #pragma unroll
        for (int j = 0; j < 9; ++j)
            gload_lds16(src + j * 1024, dst + j * 1024);
    };

    stage(blockIdx.x, 0);   // prologue: tile 0 -> buf 0

    #pragma unroll 1
    for (int k = 0; k < TILES_PER_WG; ++k) {
        asm volatile("s_waitcnt vmcnt(0)" ::: "memory");   // DMA for buf k&1 landed
        __syncthreads();                                   // + buf (k+1)&1 free (all waves done)
        if (k + 1 < TILES_PER_WG) stage(blockIdx.x + (k + 1) * NCHUNK, (k + 1) & 1);
        int b = k & 1;
        // GEMM1: G[16 x 32] per wave, K=288
        f32x4 g0 = (f32x4){0.f,0.f,0.f,0.f}, g1 = (f32x4){0.f,0.f,0.f,0.f};
        #pragma unroll
        for (int ks = 0; ks < 9; ++ks) {
            bf16x8 b0 = *(const bf16x8*)(&Ds[b][ln][ks * 32 + q * 8]);
            bf16x8 b1 = *(const bf16x8*)(&Ds[b][16 + ln][ks * 32 + q * 8]);
            g0 = __builtin_amdgcn_mfma_f32_16x16x32_bf16(fa[ks], b0, g0, 0, 0, 0);
            g1 = __builtin_amdgcn_mfma_f32_16x16x32_bf16(fa[ks], b1, g1, 0, 0, 0);
        }
        // act = ACT_CST * tanh(g); relayout C-layout -> A-layout via per-wave LDS
        #pragma unroll
        for (int nf = 0; nf < 2; ++nf) {
            #pragma unroll
            for (int r = 0; r < 4; ++r) {
                float x = (nf == 0) ? g0[r] : g1[r];
                float a = fabsf(x);
                float e = __expf(-2.f * a);
                float th = (1.f - e) / (1.f + e);
                float v = copysignf(ACT_CST * th, x);
                Gs[wave][q * 4 + r][nf * 16 + ln] = __float2bfloat16(v);
            }
        }
        // GEMM2: Out[16 x 288] += G_act[16 x 32] * Dts (own-wave Gs only: no barrier needed)
        bf16x8 a2 = *(const bf16x8*)(&Gs[wave][ln][q * 8]);
        #pragma unroll
        for (int nf = 0; nf < 18; ++nf) {
            bf16x8 b2 = *(const bf16x8*)(&Dts[b][nf * 16 + ln][q * 8]);
            acc[nf] = __builtin_amdgcn_mfma_f32_16x16x32_bf16(a2, b2, acc[nf], 0, 0, 0);
        }
    }
    // epilogue: partial[zc][batch][288]
    float* pb = part + ((size_t)blockIdx.x * NBATCH + blockIdx.y * 64 + wave * 16) * DIMP;
    #pragma unroll
    for (int nf = 0; nf < 18; ++nf) {
        #pragma unroll
        for (int r = 0; r < 4; ++r) {
            pb[(size_t)(q * 4 + r) * DIMP + nf * 16 + ln] = acc[nf][r];
        }
    }
}

// ---------- reduce partials over the 192 z-chunks: 1152 blocks, 16-way zc split
__global__ void k_reduce(const float* __restrict__ part, float* __restrict__ out) {
    __shared__ float4 red[3][16];
    int t = threadIdx.x, wave = t >> 6, lane = t & 63;
    int j = lane & 15;                 // o4 slot within block
    int zg = wave * 4 + (lane >> 4);   // 0..15 zc-group
    int o4 = blockIdx.x * 16 + j;      // 1152*16 = 18432 slots
    int b = o4 / 72, c4 = o4 % 72;
    const float* p = part + (size_t)b * DIMP + c4 * 4;
    float4 s = make_float4(0.f, 0.f, 0.f, 0.f);
    #pragma unroll 4
    for (int ii = 0; ii < 12; ++ii) {
        float4 v = *(const float4*)(p + (size_t)(zg * 12 + ii) * NBATCH * DIMP);
        s.x += v.x; s.y += v.y; s.z += v.z; s.w += v.w;
    }
    // intra-wave: fold the 4 zc-groups (lane strides 16, 32)
    s.x += __shfl_down(s.x, 16); s.y += __shfl_down(s.y, 16);
    s.z += __shfl_down(s.z, 16); s.w += __shfl_down(s.w, 16);
    s.x += __shfl_down(s.x, 32); s.y += __shfl_down(s.y, 32);
    s.z += __shfl_down(s.z, 32); s.w += __shfl_down(s.w, 32);
    if (wave > 0 && lane < 16) red[wave - 1][lane] = s;
    __syncthreads();
    if (wave == 0 && lane < 16) {
        #pragma unroll
        for (int w = 0; w < 3; ++w) {
            float4 v = red[w][lane];
            s.x += v.x; s.y += v.y; s.z += v.z; s.w += v.w;
        }
        int i0 = c4 * 4;
        float sv[4] = {s.x, s.y, s.z, s.w};
        #pragma unroll
        for (int kk = 0; kk < 4; ++kk)
            if (i0 + kk < DIM) out[b * DIM + i0 + kk] = sv[kk];
    }
}

extern "C" void kernel_launch(void* const* d_in, const int* in_sizes, int n_in,
                              void* d_out, int out_size, void* d_ws, size_t ws_size,
                              hipStream_t stream) {
    const float* F  = (const float*)d_in[0];
    const float* D  = (const float*)d_in[1];
    const float* qw = (const float*)d_in[2];
    char* ws = (char*)d_ws;
    __hip_bfloat16* Fbf = (__hip_bfloat16*)(ws + WS_FBF);
    __hip_bfloat16* Dbf = (__hip_bfloat16*)(ws + WS_DBF);
    __hip_bfloat16* Dt2 = (__hip_bfloat16*)(ws + WS_DT);
    float* part = (float*)(ws + WS_PART);

    k_prep<<<NTILES + 288, 256, 0, stream>>>(F, D, qw, Fbf, Dbf, Dt2);
    k_main<<<dim3(NCHUNK, 4), 256, 0, stream>>>(Fbf, Dbf, Dt2, part);
    k_reduce<<<1152, 256, 0, stream>>>(part, (float*)d_out);
}

// Round 8
// 159.260 us; speedup vs baseline: 1.1447x; 1.0093x over previous
//
#include <hip/hip_runtime.h>
#include <hip/hip_bf16.h>

#define DIM    286
#define DIMP   288
#define NZTOT  55296     // 48*24*48
#define NBATCH 256
#define NB_    24
#define NA_    48
#define ZC     32        // z per tile
#define NTILES 1728      // NZTOT/ZC
#define NCHUNK 192       // z-chunk workgroups (grid.x)
#define TILES_PER_WG 9   // NTILES/NCHUNK
#define S_CONST 16.911534525287763f
#define INV_S   0.05913123959890826f
#define ACT_CST 1.5927f  // normalize2mom const for tanh

typedef short bf16x8 __attribute__((ext_vector_type(8)));
typedef float f32x4  __attribute__((ext_vector_type(4)));

// ws layout (bytes)
#define WS_FBF  0u
#define WS_DBF  147456u                      // Fbf: 256*288*2
#define WS_DT   (WS_DBF + 31850496u)         // Dbf: 55296*288*2
#define WS_PART (WS_DT + 31850496u)          // Dt2: 1728 tiles * 288 * 32 * 2
                                             // part (bf16): 192*256*288*2 = 28311552

typedef const __attribute__((address_space(1))) char GA;
typedef __attribute__((address_space(3))) char LA;
__device__ __forceinline__ void gload_lds16(const void* g, void* l) {
    __builtin_amdgcn_global_load_lds((GA*)g, (LA*)l, 16, 0, 0);
}

// ---------- fused prep: blocks [0,1728) do D->Dbf/Dt2; blocks [1728,2016) do F->Fbf
// One barrier. Dbf written straight from phase-1 registers (no LDS round-trip).
// T row stride 305 dwords (odd) -> transpose column reads are 2-way bank = free.
__global__ void k_prep(const float* __restrict__ F, const float* __restrict__ D,
                       const float* __restrict__ qw,
                       __hip_bfloat16* __restrict__ Fbf,
                       __hip_bfloat16* __restrict__ Dbf, __hip_bfloat16* __restrict__ Dt2) {
    __shared__ float T[32][305];
    __shared__ float qs[24];
    int t = threadIdx.x;
    int bid = blockIdx.x;
    if (bid >= NTILES) {
        // ---- prep_f: F -> bf16 [256][288], scaled by 1/s
        int o = (bid - NTILES) * 256 + t;    // 288*256 == 73728 exactly
        int row = o / DIMP, col = o % DIMP;
        float v = (col < DIM) ? F[row * DIM + col] * INV_S : 0.f;
        Fbf[o] = __float2bfloat16(v);
        return;
    }
    int z0 = bid * 32;
    if (t < 24) qs[t] = qw[t] * S_CONST;
    // phase 1: coalesced float4 loads (32*286 = 9152 floats = 2288 float4).
    // Store fp32 to T (for the transpose) AND bf16 direct to Dbf (two 4B stores, coalesced).
    const float4* Df = (const float4*)(D + (size_t)z0 * DIM);
    for (int k = 0; k < 9; ++k) {
        int idx = t + k * 256;
        if (idx < 2288) {
            float4 v = Df[idx];
            int e = idx * 4;
            int z = e / DIM, i = e % DIM;      // i always even
            __hip_bfloat162 lo, hi;
            lo.x = __float2bfloat16(v.x); lo.y = __float2bfloat16(v.y);
            hi.x = __float2bfloat16(v.z); hi.y = __float2bfloat16(v.w);
            T[z][i] = v.x; T[z][i + 1] = v.y;
            *(__hip_bfloat162*)(Dbf + (size_t)(z0 + z) * DIMP + i) = lo;
            if (i == 284) {   // i==284 => z even => z+1 <= 31
                T[z + 1][0] = v.z; T[z + 1][1] = v.w;
                *(__hip_bfloat162*)(Dbf + (size_t)(z0 + z + 1) * DIMP) = hi;
            } else {
                T[z][i + 2] = v.z; T[z][i + 3] = v.w;
                *(__hip_bfloat162*)(Dbf + (size_t)(z0 + z) * DIMP + i + 2) = hi;
            }
        }
    }
    if (t < 32) {   // zero K-pad cols 286..287 of Dbf
        __hip_bfloat162 zz; zz.x = __float2bfloat16(0.f); zz.y = zz.x;
        *(__hip_bfloat162*)(Dbf + (size_t)(z0 + t) * DIMP + DIM) = zz;
    }
    __syncthreads();
    // phase 2: Dt2[tz][i][z] transpose: 288 i * 4 zc = 1152 fully-contiguous 16B writes
    for (int s = 0; s < 5; ++s) {
        int idx = t + s * 256;
        if (idx < 1152) {
            int i = idx >> 2, zc = idx & 3;
            __hip_bfloat16 o8[8];
            #pragma unroll
            for (int j = 0; j < 8; ++j) {
                int zl = zc * 8 + j;
                int y = ((z0 + zl) / NA_) % NB_;
                o8[j] = __float2bfloat16(T[zl][i] * qs[y]);
            }
            *(bf16x8*)(Dt2 + ((size_t)bid * DIMP + i) * ZC + zc * 8) = *(const bf16x8*)o8;
        }
    }
}

// ---------- fused main: single-buffer, 2 barriers/tile, DMA staging, 40960B LDS -> 4 blocks/CU.
__launch_bounds__(256, 4)
__global__ void k_main(const __hip_bfloat16* __restrict__ Fbf,
                       const __hip_bfloat16* __restrict__ Dbf,
                       const __hip_bfloat16* __restrict__ Dt2,
                       __hip_bfloat16* __restrict__ part) {
    __shared__ __align__(16) __hip_bfloat16 Ds[32][288];    // [z][i]  18432 B
    __shared__ __align__(16) __hip_bfloat16 Dts[288][32];   // [i][z]  18432 B
    __shared__ __align__(16) __hip_bfloat16 Gs[4][16][32];  // 4096 B -> total 40960 B

    int t = threadIdx.x;
    int wave = t >> 6, lane = t & 63, ln = lane & 15, q = lane >> 4;

    // cache F A-frags for this wave's 16 batch rows (9 K-steps of 32)
    bf16x8 fa[9];
    int row = blockIdx.y * 64 + wave * 16 + ln;
    const __hip_bfloat16* fp = Fbf + (size_t)row * DIMP + q * 8;
    #pragma unroll
    for (int ks = 0; ks < 9; ++ks) fa[ks] = *(const bf16x8*)(fp + ks * 32);

    f32x4 acc[18];
    #pragma unroll
    for (int n = 0; n < 18; ++n) acc[n] = (f32x4){0.f, 0.f, 0.f, 0.f};

    #pragma unroll 1
    for (int k = 0; k < TILES_PER_WG; ++k) {
        int tz = blockIdx.x + k * NCHUNK;
        // stage: waves 0,1 -> Ds halves; waves 2,3 -> Dts halves; 9x1KB DMA each
        {
            const char* src; char* dst;
            if (wave < 2) {
                src = (const char*)(Dbf + (size_t)tz * ZC * DIMP) + wave * 9216 + lane * 16;
                dst = ((char*)&Ds[0][0]) + wave * 9216;
            } else {
                src = (const char*)(Dt2 + (size_t)tz * DIMP * ZC) + (wave - 2) * 9216 + lane * 16;
                dst = ((char*)&Dts[0][0]) + (wave - 2) * 9216;
            }
            #pragma unroll
            for (int j = 0; j < 9; ++j)
                gload_lds16(src + j * 1024, dst + j * 1024);
        }
        asm volatile("s_waitcnt vmcnt(0)" ::: "memory");   // DMA landed
        __syncthreads();
        // GEMM1: G[16 x 32] per wave, K=288
        f32x4 g0 = (f32x4){0.f,0.f,0.f,0.f}, g1 = (f32x4){0.f,0.f,0.f,0.f};
        #pragma unroll
        for (int ks = 0; ks < 9; ++ks) {
            bf16x8 b0 = *(const bf16x8*)(&Ds[ln][ks * 32 + q * 8]);
            bf16x8 b1 = *(const bf16x8*)(&Ds[16 + ln][ks * 32 + q * 8]);
            g0 = __builtin_amdgcn_mfma_f32_16x16x32_bf16(fa[ks], b0, g0, 0, 0, 0);
            g1 = __builtin_amdgcn_mfma_f32_16x16x32_bf16(fa[ks], b1, g1, 0, 0, 0);
        }
        // act = ACT_CST * tanh(g); relayout C-layout -> A-layout via per-wave LDS
        #pragma unroll
        for (int nf = 0; nf < 2; ++nf) {
            #pragma unroll
            for (int r = 0; r < 4; ++r) {
                float x = (nf == 0) ? g0[r] : g1[r];
                float a = fabsf(x);
                float e = __expf(-2.f * a);
                float th = (1.f - e) / (1.f + e);
                float v = copysignf(ACT_CST * th, x);
                Gs[wave][q * 4 + r][nf * 16 + ln] = __float2bfloat16(v);
            }
        }
        // GEMM2: Out[16 x 288] += G_act[16 x 32] * Dts (own-wave Gs only: no barrier needed)
        bf16x8 a2 = *(const bf16x8*)(&Gs[wave][ln][q * 8]);
        #pragma unroll
        for (int nf = 0; nf < 18; ++nf) {
            bf16x8 b2 = *(const bf16x8*)(&Dts[nf * 16 + ln][q * 8]);
            acc[nf] = __builtin_amdgcn_mfma_f32_16x16x32_bf16(a2, b2, acc[nf], 0, 0, 0);
        }
        __syncthreads();   // protect Ds/Dts before next stage
    }
    // epilogue: partial[zc][batch][288] in bf16 (halves the write traffic)
    __hip_bfloat16* pb = part + ((size_t)blockIdx.x * NBATCH + blockIdx.y * 64 + wave * 16) * DIMP;
    #pragma unroll
    for (int nf = 0; nf < 18; ++nf) {
        #pragma unroll
        for (int r = 0; r < 4; ++r) {
            pb[(size_t)(q * 4 + r) * DIMP + nf * 16 + ln] = __float2bfloat16(acc[nf][r]);
        }
    }
}

// ---------- reduce bf16 partials over the 192 z-chunks: 576 blocks, 16-way zc split
__global__ void k_reduce(const __hip_bfloat16* __restrict__ part, float* __restrict__ out) {
    __shared__ float red[3][16][8];
    int t = threadIdx.x, wave = t >> 6, lane = t & 63;
    int j = lane & 15;                 // o8 slot within block
    int zg = wave * 4 + (lane >> 4);   // 0..15 zc-group
    int o8 = blockIdx.x * 16 + j;      // 576*16 = 9216 slots = 256 rows * 36 col8
    int b = o8 / 36, c8 = o8 % 36;
    const __hip_bfloat16* p = part + (size_t)b * DIMP + c8 * 8;
    float s[8];
    #pragma unroll
    for (int kk = 0; kk < 8; ++kk) s[kk] = 0.f;
    #pragma unroll 4
    for (int ii = 0; ii < 12; ++ii) {
        bf16x8 v = *(const bf16x8*)(p + (size_t)(zg * 12 + ii) * NBATCH * DIMP);
        #pragma unroll
        for (int kk = 0; kk < 8; ++kk) {
            __hip_bfloat16 h; *(short*)&h = v[kk];
            s[kk] += __bfloat162float(h);
        }
    }
    // intra-wave: fold the 4 zc-groups (lane strides 16, 32)
    #pragma unroll
    for (int kk = 0; kk < 8; ++kk) {
        s[kk] += __shfl_down(s[kk], 16);
        s[kk] += __shfl_down(s[kk], 32);
    }
    if (wave > 0 && lane < 16) {
        #pragma unroll
        for (int kk = 0; kk < 8; ++kk) red[wave - 1][lane][kk] = s[kk];
    }
    __syncthreads();
    if (wave == 0 && lane < 16) {
        #pragma unroll
        for (int w = 0; w < 3; ++w)
            #pragma unroll
            for (int kk = 0; kk < 8; ++kk) s[kk] += red[w][lane][kk];
        int i0 = c8 * 8;
        #pragma unroll
        for (int kk = 0; kk < 8; ++kk)
            if (i0 + kk < DIM) out[b * DIM + i0 + kk] = s[kk];
    }
}

extern "C" void kernel_launch(void* const* d_in, const int* in_sizes, int n_in,
                              void* d_out, int out_size, void* d_ws, size_t ws_size,
                              hipStream_t stream) {
    const float* F  = (const float*)d_in[0];
    const float* D  = (const float*)d_in[1];
    const float* qw = (const float*)d_in[2];
    char* ws = (char*)d_ws;
    __hip_bfloat16* Fbf = (__hip_bfloat16*)(ws + WS_FBF);
    __hip_bfloat16* Dbf = (__hip_bfloat16*)(ws + WS_DBF);
    __hip_bfloat16* Dt2 = (__hip_bfloat16*)(ws + WS_DT);
    __hip_bfloat16* part = (__hip_bfloat16*)(ws + WS_PART);

    k_prep<<<NTILES + 288, 256, 0, stream>>>(F, D, qw, Fbf, Dbf, Dt2);
    k_main<<<dim3(NCHUNK, 4), 256, 0, stream>>>(Fbf, Dbf, Dt2, part);
    k_reduce<<<576, 256, 0, stream>>>(part, (float*)d_out);
}

// Round 9
// 149.106 us; speedup vs baseline: 1.2226x; 1.0681x over previous
//
#include <hip/hip_runtime.h>
#include <hip/hip_bf16.h>

#define DIM    286
#define DIMP   288
#define NZTOT  55296     // 48*24*48
#define NBATCH 256
#define NB_    24
#define NA_    48
#define ZC     32        // z per tile
#define NTILES 1728      // NZTOT/ZC
#define NCHUNK 192       // z-chunk workgroups (grid.x)
#define TILES_PER_WG 9   // NTILES/NCHUNK
#define S_CONST 16.911534525287763f
#define INV_S   0.05913123959890826f
#define ACT_CST 1.5927f  // normalize2mom const for tanh

typedef short bf16x8 __attribute__((ext_vector_type(8)));
typedef float f32x4  __attribute__((ext_vector_type(4)));

// ws layout (bytes)
#define WS_FBF  0u
#define WS_DBF  147456u                      // Fbf: 256*288*2
#define WS_DT   (WS_DBF + 31850496u)         // Dbf: 55296*288*2
#define WS_PART (WS_DT + 31850496u)          // Dt2: 1728 tiles * 288 * 32 * 2
                                             // part (bf16): 192*256*288*2 = 28311552

typedef const __attribute__((address_space(1))) char GA;
typedef __attribute__((address_space(3))) char LA;
__device__ __forceinline__ void gload_lds16(const void* g, void* l) {
    __builtin_amdgcn_global_load_lds((GA*)g, (LA*)l, 16, 0, 0);
}

// ---------- fused prep: blocks [0,1728) do D->Dbf/Dt2; blocks [1728,2016) do F->Fbf
__global__ void k_prep(const float* __restrict__ F, const float* __restrict__ D,
                       const float* __restrict__ qw,
                       __hip_bfloat16* __restrict__ Fbf,
                       __hip_bfloat16* __restrict__ Dbf, __hip_bfloat16* __restrict__ Dt2) {
    __shared__ float T[32][305];
    __shared__ float qs[24];
    int t = threadIdx.x;
    int bid = blockIdx.x;
    if (bid >= NTILES) {
        // ---- prep_f: F -> bf16 [256][288], scaled by 1/s
        int o = (bid - NTILES) * 256 + t;    // 288*256 == 73728 exactly
        int row = o / DIMP, col = o % DIMP;
        float v = (col < DIM) ? F[row * DIM + col] * INV_S : 0.f;
        Fbf[o] = __float2bfloat16(v);
        return;
    }
    int z0 = bid * 32;
    if (t < 24) qs[t] = qw[t] * S_CONST;
    // phase 1: coalesced float4 loads; fp32 to T AND bf16 direct to Dbf.
    const float4* Df = (const float4*)(D + (size_t)z0 * DIM);
    for (int k = 0; k < 9; ++k) {
        int idx = t + k * 256;
        if (idx < 2288) {
            float4 v = Df[idx];
            int e = idx * 4;
            int z = e / DIM, i = e % DIM;      // i always even
            __hip_bfloat162 lo, hi;
            lo.x = __float2bfloat16(v.x); lo.y = __float2bfloat16(v.y);
            hi.x = __float2bfloat16(v.z); hi.y = __float2bfloat16(v.w);
            T[z][i] = v.x; T[z][i + 1] = v.y;
            *(__hip_bfloat162*)(Dbf + (size_t)(z0 + z) * DIMP + i) = lo;
            if (i == 284) {   // i==284 => z even => z+1 <= 31
                T[z + 1][0] = v.z; T[z + 1][1] = v.w;
                *(__hip_bfloat162*)(Dbf + (size_t)(z0 + z + 1) * DIMP) = hi;
            } else {
                T[z][i + 2] = v.z; T[z][i + 3] = v.w;
                *(__hip_bfloat162*)(Dbf + (size_t)(z0 + z) * DIMP + i + 2) = hi;
            }
        }
    }
    if (t < 32) {   // zero K-pad cols 286..287 of Dbf
        __hip_bfloat162 zz; zz.x = __float2bfloat16(0.f); zz.y = zz.x;
        *(__hip_bfloat162*)(Dbf + (size_t)(z0 + t) * DIMP + DIM) = zz;
    }
    __syncthreads();
    // phase 2: Dt2[tz][i][z] transpose: 288 i * 4 zc = 1152 contiguous 16B writes
    for (int s = 0; s < 5; ++s) {
        int idx = t + s * 256;
        if (idx < 1152) {
            int i = idx >> 2, zc = idx & 3;
            __hip_bfloat16 o8[8];
            #pragma unroll
            for (int j = 0; j < 8; ++j) {
                int zl = zc * 8 + j;
                int y = ((z0 + zl) / NA_) % NB_;
                o8[j] = __float2bfloat16(T[zl][i] * qs[y]);
            }
            *(bf16x8*)(Dt2 + ((size_t)bid * DIMP + i) * ZC + zc * 8) = *(const bf16x8*)o8;
        }
    }
}

// ---------- fused main, M=32 per wave: B-fragments amortized over 2 row-halves.
// grid (192, 2); block 256; wave owns rows by*128 + wave*32 .. +31.
__launch_bounds__(256, 2)
__global__ void k_main(const __hip_bfloat16* __restrict__ Fbf,
                       const __hip_bfloat16* __restrict__ Dbf,
                       const __hip_bfloat16* __restrict__ Dt2,
                       __hip_bfloat16* __restrict__ part) {
    __shared__ __align__(16) __hip_bfloat16 Ds[32][288];    // [z][i]  18432 B
    __shared__ __align__(16) __hip_bfloat16 Dts[288][32];   // [i][z]  18432 B
    __shared__ __align__(16) __hip_bfloat16 Gs[4][32][32];  // 8192 B -> total 45056 B

    int t = threadIdx.x;
    int wave = t >> 6, lane = t & 63, ln = lane & 15, q = lane >> 4;

    // cache F A-frags for this wave's 32 batch rows (2 halves x 9 K-steps)
    bf16x8 fa[2][9];
    int rowbase = blockIdx.y * 128 + wave * 32;
    #pragma unroll
    for (int h = 0; h < 2; ++h) {
        const __hip_bfloat16* fp = Fbf + (size_t)(rowbase + h * 16 + ln) * DIMP + q * 8;
        #pragma unroll
        for (int ks = 0; ks < 9; ++ks) fa[h][ks] = *(const bf16x8*)(fp + ks * 32);
    }

    f32x4 acc[2][18];
    #pragma unroll
    for (int h = 0; h < 2; ++h)
        #pragma unroll
        for (int n = 0; n < 18; ++n) acc[h][n] = (f32x4){0.f, 0.f, 0.f, 0.f};

    #pragma unroll 1
    for (int k = 0; k < TILES_PER_WG; ++k) {
        int tz = blockIdx.x + k * NCHUNK;
        // stage: waves 0,1 -> Ds halves; waves 2,3 -> Dts halves; 9x1KB DMA each
        {
            const char* src; char* dst;
            if (wave < 2) {
                src = (const char*)(Dbf + (size_t)tz * ZC * DIMP) + wave * 9216 + lane * 16;
                dst = ((char*)&Ds[0][0]) + wave * 9216;
            } else {
                src = (const char*)(Dt2 + (size_t)tz * DIMP * ZC) + (wave - 2) * 9216 + lane * 16;
                dst = ((char*)&Dts[0][0]) + (wave - 2) * 9216;
            }
            #pragma unroll
            for (int j = 0; j < 9; ++j)
                gload_lds16(src + j * 1024, dst + j * 1024);
        }
        asm volatile("s_waitcnt vmcnt(0)" ::: "memory");   // DMA landed
        __syncthreads();
        // GEMM1: G[32 x 32] per wave, K=288; B-frags read once for 2 row-halves
        f32x4 g00 = (f32x4){0.f,0.f,0.f,0.f}, g01 = (f32x4){0.f,0.f,0.f,0.f};
        f32x4 g10 = (f32x4){0.f,0.f,0.f,0.f}, g11 = (f32x4){0.f,0.f,0.f,0.f};
        #pragma unroll
        for (int ks = 0; ks < 9; ++ks) {
            bf16x8 b0 = *(const bf16x8*)(&Ds[ln][ks * 32 + q * 8]);
            bf16x8 b1 = *(const bf16x8*)(&Ds[16 + ln][ks * 32 + q * 8]);
            g00 = __builtin_amdgcn_mfma_f32_16x16x32_bf16(fa[0][ks], b0, g00, 0, 0, 0);
            g01 = __builtin_amdgcn_mfma_f32_16x16x32_bf16(fa[0][ks], b1, g01, 0, 0, 0);
            g10 = __builtin_amdgcn_mfma_f32_16x16x32_bf16(fa[1][ks], b0, g10, 0, 0, 0);
            g11 = __builtin_amdgcn_mfma_f32_16x16x32_bf16(fa[1][ks], b1, g11, 0, 0, 0);
        }
        // act + C-layout -> A-layout relayout (per-wave LDS, no barrier)
        #pragma unroll
        for (int h = 0; h < 2; ++h) {
            #pragma unroll
            for (int zh = 0; zh < 2; ++zh) {
                f32x4 g = (h == 0) ? (zh == 0 ? g00 : g01) : (zh == 0 ? g10 : g11);
                #pragma unroll
                for (int r = 0; r < 4; ++r) {
                    float x = g[r];
                    float a = fabsf(x);
                    float e = __expf(-2.f * a);
                    float th = (1.f - e) / (1.f + e);
                    float v = copysignf(ACT_CST * th, x);
                    Gs[wave][h * 16 + q * 4 + r][zh * 16 + ln] = __float2bfloat16(v);
                }
            }
        }
        // GEMM2: Out[32 x 288] += P[32 x 32] * Dts; B-frags read once for 2 row-halves
        bf16x8 a20 = *(const bf16x8*)(&Gs[wave][ln][q * 8]);
        bf16x8 a21 = *(const bf16x8*)(&Gs[wave][16 + ln][q * 8]);
        #pragma unroll
        for (int nf = 0; nf < 18; ++nf) {
            bf16x8 b2 = *(const bf16x8*)(&Dts[nf * 16 + ln][q * 8]);
            acc[0][nf] = __builtin_amdgcn_mfma_f32_16x16x32_bf16(a20, b2, acc[0][nf], 0, 0, 0);
            acc[1][nf] = __builtin_amdgcn_mfma_f32_16x16x32_bf16(a21, b2, acc[1][nf], 0, 0, 0);
        }
        __syncthreads();   // protect Ds/Dts before next stage
    }
    // epilogue: partial[zc][batch][288] in bf16
    #pragma unroll
    for (int h = 0; h < 2; ++h) {
        __hip_bfloat16* pb = part + ((size_t)blockIdx.x * NBATCH + rowbase + h * 16) * DIMP;
        #pragma unroll
        for (int nf = 0; nf < 18; ++nf) {
            #pragma unroll
            for (int r = 0; r < 4; ++r) {
                pb[(size_t)(q * 4 + r) * DIMP + nf * 16 + ln] = __float2bfloat16(acc[h][nf][r]);
            }
        }
    }
}

// ---------- reduce bf16 partials over the 192 z-chunks: 576 blocks, 16-way zc split
__global__ void k_reduce(const __hip_bfloat16* __restrict__ part, float* __restrict__ out) {
    __shared__ float red[3][16][8];
    int t = threadIdx.x, wave = t >> 6, lane = t & 63;
    int j = lane & 15;                 // o8 slot within block
    int zg = wave * 4 + (lane >> 4);   // 0..15 zc-group
    int o8 = blockIdx.x * 16 + j;      // 576*16 = 9216 slots = 256 rows * 36 col8
    int b = o8 / 36, c8 = o8 % 36;
    const __hip_bfloat16* p = part + (size_t)b * DIMP + c8 * 8;
    float s[8];
    #pragma unroll
    for (int kk = 0; kk < 8; ++kk) s[kk] = 0.f;
    #pragma unroll 4
    for (int ii = 0; ii < 12; ++ii) {
        bf16x8 v = *(const bf16x8*)(p + (size_t)(zg * 12 + ii) * NBATCH * DIMP);
        #pragma unroll
        for (int kk = 0; kk < 8; ++kk) {
            __hip_bfloat16 h; *(short*)&h = v[kk];
            s[kk] += __bfloat162float(h);
        }
    }
    // intra-wave: fold the 4 zc-groups (lane strides 16, 32)
    #pragma unroll
    for (int kk = 0; kk < 8; ++kk) {
        s[kk] += __shfl_down(s[kk], 16);
        s[kk] += __shfl_down(s[kk], 32);
    }
    if (wave > 0 && lane < 16) {
        #pragma unroll
        for (int kk = 0; kk < 8; ++kk) red[wave - 1][lane][kk] = s[kk];
    }
    __syncthreads();
    if (wave == 0 && lane < 16) {
        #pragma unroll
        for (int w = 0; w < 3; ++w)
            #pragma unroll
            for (int kk = 0; kk < 8; ++kk) s[kk] += red[w][lane][kk];
        int i0 = c8 * 8;
        #pragma unroll
        for (int kk = 0; kk < 8; ++kk)
            if (i0 + kk < DIM) out[b * DIM + i0 + kk] = s[kk];
    }
}

extern "C" void kernel_launch(void* const* d_in, const int* in_sizes, int n_in,
                              void* d_out, int out_size, void* d_ws, size_t ws_size,
                              hipStream_t stream) {
    const float* F  = (const float*)d_in[0];
    const float* D  = (const float*)d_in[1];
    const float* qw = (const float*)d_in[2];
    char* ws = (char*)d_ws;
    __hip_bfloat16* Fbf = (__hip_bfloat16*)(ws + WS_FBF);
    __hip_bfloat16* Dbf = (__hip_bfloat16*)(ws + WS_DBF);
    __hip_bfloat16* Dt2 = (__hip_bfloat16*)(ws + WS_DT);
    __hip_bfloat16* part = (__hip_bfloat16*)(ws + WS_PART);

    k_prep<<<NTILES + 288, 256, 0, stream>>>(F, D, qw, Fbf, Dbf, Dt2);
    k_main<<<dim3(NCHUNK, 2), 256, 0, stream>>>(Fbf, Dbf, Dt2, part);
    k_reduce<<<576, 256, 0, stream>>>(part, (float*)d_out);
}

// Round 10
// 142.063 us; speedup vs baseline: 1.2832x; 1.0496x over previous
//
#include <hip/hip_runtime.h>
#include <hip/hip_bf16.h>

#define DIM    286
#define DIMP   288
#define NZTOT  55296     // 48*24*48
#define NBATCH 256
#define NB_    24
#define NA_    48
#define ZC     32        // z per tile
#define NTILES 1728      // NZTOT/ZC
#define NCHUNK 192       // z-chunk workgroups (grid.x)
#define TILES_PER_WG 9   // NTILES/NCHUNK
#define S_CONST 16.911534525287763f
#define INV_S   0.05913123959890826f
#define ACT_CST 1.5927f  // normalize2mom const for tanh

typedef short bf16x8 __attribute__((ext_vector_type(8)));
typedef float f32x4  __attribute__((ext_vector_type(4)));

// ws layout (bytes)
#define WS_FBF  0u
#define WS_DBF  147456u                      // Fbf: 256*288*2
#define WS_DT   (WS_DBF + 31850496u)         // Dbf: 55296*288*2
#define WS_PART (WS_DT + 31850496u)          // Dt2: 1728 tiles * 288 * 32 * 2
                                             // part (bf16): 192*256*288*2 = 28311552

typedef const __attribute__((address_space(1))) char GA;
typedef __attribute__((address_space(3))) char LA;
__device__ __forceinline__ void gload_lds16(const void* g, void* l) {
    __builtin_amdgcn_global_load_lds((GA*)g, (LA*)l, 16, 0, 0);
}

// ---------- fused prep: blocks [0,1728) do D->Dbf/Dt2 via DMA-flat LDS; [1728,2016) F->Fbf
__global__ void k_prep(const float* __restrict__ F, const float* __restrict__ D,
                       const float* __restrict__ qw,
                       __hip_bfloat16* __restrict__ Fbf,
                       __hip_bfloat16* __restrict__ Dbf, __hip_bfloat16* __restrict__ Dt2) {
    __shared__ __align__(16) float T[9152];   // flat 32*286 fp32 = 36608 B
    __shared__ float qs[24];
    int t = threadIdx.x;
    int bid = blockIdx.x;
    if (bid >= NTILES) {
        // ---- prep_f: F -> bf16 [256][288], scaled by 1/s
        int o = (bid - NTILES) * 256 + t;    // 288*256 == 73728 exactly
        int row = o / DIMP, col = o % DIMP;
        float v = (col < DIM) ? F[row * DIM + col] * INV_S : 0.f;
        Fbf[o] = __float2bfloat16(v);
        return;
    }
    int z0 = bid * 32;
    if (t < 24) qs[t] = qw[t] * S_CONST;
    // DMA: 36608 B = 35 full 1KB chunks + 768 B tail (48 lanes)
    {
        int wave = t >> 6, lane = t & 63;
        const char* src = (const char*)(D + (size_t)z0 * DIM);
        char* dst = (char*)T;
        #pragma unroll
        for (int j = 0; j < 9; ++j) {
            int c = wave + j * 4;
            if (c < 35 || (c == 35 && lane < 48))
                gload_lds16(src + c * 1024 + lane * 16, dst + c * 1024);
        }
    }
    asm volatile("s_waitcnt vmcnt(0)" ::: "memory");
    __syncthreads();
    // Dbf: lane-consecutive float2 -> bf162, 4608 dwords (18 iters), conflict-free b64 reads
    for (int m = 0; m < 18; ++m) {
        int d = t + m * 256;                 // 0..4607
        int z = d / 144, i2 = d % 144;
        int i = i2 * 2;
        __hip_bfloat162 o2;
        if (i < DIM) {
            float2 v = *(const float2*)(&T[z * DIM + i]);   // z*286+i even -> 8B aligned
            o2.x = __float2bfloat16(v.x); o2.y = __float2bfloat16(v.y);
        } else {
            o2.x = __float2bfloat16(0.f); o2.y = o2.x;      // pad cols 286..287
        }
        *(__hip_bfloat162*)(Dbf + (size_t)(z0 + z) * DIMP + i) = o2;
    }
    // Dt2[tz][i][z] transpose: 288 i * 4 zc = 1152 contiguous 16B writes
    for (int s = 0; s < 5; ++s) {
        int idx = t + s * 256;
        if (idx < 1152) {
            int i = idx >> 2, zc = idx & 3;
            __hip_bfloat16 o8[8];
            #pragma unroll
            for (int j = 0; j < 8; ++j) {
                int zl = zc * 8 + j;
                int y = ((z0 + zl) / NA_) % NB_;
                o8[j] = __float2bfloat16(T[zl * DIM + i] * qs[y]);
            }
            *(bf16x8*)(Dt2 + ((size_t)bid * DIMP + i) * ZC + zc * 8) = *(const bf16x8*)o8;
        }
    }
}

// ---------- fused main, M=32 per wave; epilogue packs acc into coalesced b128 stores
// in a permuted layout that k_reduce decodes.
__launch_bounds__(256, 2)
__global__ void k_main(const __hip_bfloat16* __restrict__ Fbf,
                       const __hip_bfloat16* __restrict__ Dbf,
                       const __hip_bfloat16* __restrict__ Dt2,
                       __hip_bfloat16* __restrict__ part) {
    __shared__ __align__(16) __hip_bfloat16 Ds[32][288];    // [z][i]  18432 B
    __shared__ __align__(16) __hip_bfloat16 Dts[288][32];   // [i][z]  18432 B
    __shared__ __align__(16) __hip_bfloat16 Gs[4][32][32];  // 8192 B -> total 45056 B

    int t = threadIdx.x;
    int wave = t >> 6, lane = t & 63, ln = lane & 15, q = lane >> 4;

    // cache F A-frags for this wave's 32 batch rows (2 halves x 9 K-steps)
    bf16x8 fa[2][9];
    int rowbase = blockIdx.y * 128 + wave * 32;
    #pragma unroll
    for (int h = 0; h < 2; ++h) {
        const __hip_bfloat16* fp = Fbf + (size_t)(rowbase + h * 16 + ln) * DIMP + q * 8;
        #pragma unroll
        for (int ks = 0; ks < 9; ++ks) fa[h][ks] = *(const bf16x8*)(fp + ks * 32);
    }

    f32x4 acc[2][18];
    #pragma unroll
    for (int h = 0; h < 2; ++h)
        #pragma unroll
        for (int n = 0; n < 18; ++n) acc[h][n] = (f32x4){0.f, 0.f, 0.f, 0.f};

    #pragma unroll 1
    for (int k = 0; k < TILES_PER_WG; ++k) {
        int tz = blockIdx.x + k * NCHUNK;
        // stage: waves 0,1 -> Ds halves; waves 2,3 -> Dts halves; 9x1KB DMA each
        {
            const char* src; char* dst;
            if (wave < 2) {
                src = (const char*)(Dbf + (size_t)tz * ZC * DIMP) + wave * 9216 + lane * 16;
                dst = ((char*)&Ds[0][0]) + wave * 9216;
            } else {
                src = (const char*)(Dt2 + (size_t)tz * DIMP * ZC) + (wave - 2) * 9216 + lane * 16;
                dst = ((char*)&Dts[0][0]) + (wave - 2) * 9216;
            }
            #pragma unroll
            for (int j = 0; j < 9; ++j)
                gload_lds16(src + j * 1024, dst + j * 1024);
        }
        asm volatile("s_waitcnt vmcnt(0)" ::: "memory");   // DMA landed
        __syncthreads();
        // GEMM1: G[32 x 32] per wave, K=288; B-frags read once for 2 row-halves
        f32x4 g00 = (f32x4){0.f,0.f,0.f,0.f}, g01 = (f32x4){0.f,0.f,0.f,0.f};
        f32x4 g10 = (f32x4){0.f,0.f,0.f,0.f}, g11 = (f32x4){0.f,0.f,0.f,0.f};
        #pragma unroll
        for (int ks = 0; ks < 9; ++ks) {
            bf16x8 b0 = *(const bf16x8*)(&Ds[ln][ks * 32 + q * 8]);
            bf16x8 b1 = *(const bf16x8*)(&Ds[16 + ln][ks * 32 + q * 8]);
            g00 = __builtin_amdgcn_mfma_f32_16x16x32_bf16(fa[0][ks], b0, g00, 0, 0, 0);
            g01 = __builtin_amdgcn_mfma_f32_16x16x32_bf16(fa[0][ks], b1, g01, 0, 0, 0);
            g10 = __builtin_amdgcn_mfma_f32_16x16x32_bf16(fa[1][ks], b0, g10, 0, 0, 0);
            g11 = __builtin_amdgcn_mfma_f32_16x16x32_bf16(fa[1][ks], b1, g11, 0, 0, 0);
        }
        // act + C-layout -> A-layout relayout (per-wave LDS, no barrier)
        #pragma unroll
        for (int h = 0; h < 2; ++h) {
            #pragma unroll
            for (int zh = 0; zh < 2; ++zh) {
                f32x4 g = (h == 0) ? (zh == 0 ? g00 : g01) : (zh == 0 ? g10 : g11);
                #pragma unroll
                for (int r = 0; r < 4; ++r) {
                    float x = g[r];
                    float a = fabsf(x);
                    float e = __expf(-2.f * a);
                    float th = (1.f - e) / (1.f + e);
                    float v = copysignf(ACT_CST * th, x);
                    Gs[wave][h * 16 + q * 4 + r][zh * 16 + ln] = __float2bfloat16(v);
                }
            }
        }
        // GEMM2: Out[32 x 288] += P[32 x 32] * Dts; B-frags read once for 2 row-halves
        bf16x8 a20 = *(const bf16x8*)(&Gs[wave][ln][q * 8]);
        bf16x8 a21 = *(const bf16x8*)(&Gs[wave][16 + ln][q * 8]);
        #pragma unroll
        for (int nf = 0; nf < 18; ++nf) {
            bf16x8 b2 = *(const bf16x8*)(&Dts[nf * 16 + ln][q * 8]);
            acc[0][nf] = __builtin_amdgcn_mfma_f32_16x16x32_bf16(a20, b2, acc[0][nf], 0, 0, 0);
            acc[1][nf] = __builtin_amdgcn_mfma_f32_16x16x32_bf16(a21, b2, acc[1][nf], 0, 0, 0);
        }
        __syncthreads();   // protect Ds/Dts before next stage
    }
    // epilogue: permuted coalesced layout, 18 b128 stores/thread.
    // elem ((h*9+m)*64 + lane)*8 + j  <=>  acc[h][2m + (j>>2)][j&3]
    // i.e. row = wr*32 + h*16 + q*4 + (j&3), i = (2m + (j>>2))*16 + ln, wr = by*4+wave
    __hip_bfloat16* pw = part + (size_t)blockIdx.x * (NBATCH * DIMP)
                       + ((size_t)blockIdx.y * 128 + wave * 32) * DIMP;
    #pragma unroll
    for (int h = 0; h < 2; ++h) {
        #pragma unroll
        for (int m = 0; m < 9; ++m) {
            __hip_bfloat16 o8[8];
            #pragma unroll
            for (int j = 0; j < 8; ++j)
                o8[j] = __float2bfloat16(acc[h][2 * m + (j >> 2)][j & 3]);
            *(bf16x8*)(pw + (size_t)((h * 9 + m) * 64 + lane) * 8) = *(const bf16x8*)o8;
        }
    }
}

// ---------- reduce permuted bf16 partials over 192 z-chunks: 576 blocks x 16 slots
__global__ void k_reduce(const __hip_bfloat16* __restrict__ part, float* __restrict__ out) {
    __shared__ float red[3][16][8];
    int t = threadIdx.x, wave = t >> 6, lane = t & 63;
    int j = lane & 15;                 // slot within block
    int zg = wave * 4 + (lane >> 4);   // 0..15 zc-group
    int s = blockIdx.x * 16 + j;       // 576*16 = 9216 b128 slots per chunk
    const __hip_bfloat16* p = part + (size_t)s * 8;
    float sum[8];
    #pragma unroll
    for (int kk = 0; kk < 8; ++kk) sum[kk] = 0.f;
    #pragma unroll 4
    for (int ii = 0; ii < 12; ++ii) {
        bf16x8 v = *(const bf16x8*)(p + (size_t)(zg * 12 + ii) * (NBATCH * DIMP));
        #pragma unroll
        for (int kk = 0; kk < 8; ++kk) {
            __hip_bfloat16 h; *(short*)&h = v[kk];
            sum[kk] += __bfloat162float(h);
        }
    }
    // intra-wave: fold the 4 zc-groups (lane strides 16, 32)
    #pragma unroll
    for (int kk = 0; kk < 8; ++kk) {
        sum[kk] += __shfl_down(sum[kk], 16);
        sum[kk] += __shfl_down(sum[kk], 32);
    }
    if (wave > 0 && lane < 16) {
        #pragma unroll
        for (int kk = 0; kk < 8; ++kk) red[wave - 1][lane][kk] = sum[kk];
    }
    __syncthreads();
    if (wave == 0 && lane < 16) {
        #pragma unroll
        for (int w = 0; w < 3; ++w)
            #pragma unroll
            for (int kk = 0; kk < 8; ++kk) sum[kk] += red[w][lane][kk];
        // decode slot s -> (rows, cols)
        int wr = s / 1152, si = s % 1152;
        int lane_m = si % 64, m9 = si / 64;
        int h = m9 / 9, m = m9 % 9, q = lane_m >> 4, ln = lane_m & 15;
        int rowb = wr * 32 + h * 16 + q * 4;
        #pragma unroll
        for (int j8 = 0; j8 < 8; ++j8) {
            int nf = 2 * m + (j8 >> 2), r = j8 & 3;
            int i = nf * 16 + ln;
            if (i < DIM) out[(rowb + r) * DIM + i] = sum[j8];
        }
    }
}

extern "C" void kernel_launch(void* const* d_in, const int* in_sizes, int n_in,
                              void* d_out, int out_size, void* d_ws, size_t ws_size,
                              hipStream_t stream) {
    const float* F  = (const float*)d_in[0];
    const float* D  = (const float*)d_in[1];
    const float* qw = (const float*)d_in[2];
    char* ws = (char*)d_ws;
    __hip_bfloat16* Fbf = (__hip_bfloat16*)(ws + WS_FBF);
    __hip_bfloat16* Dbf = (__hip_bfloat16*)(ws + WS_DBF);
    __hip_bfloat16* Dt2 = (__hip_bfloat16*)(ws + WS_DT);
    __hip_bfloat16* part = (__hip_bfloat16*)(ws + WS_PART);

    k_prep<<<NTILES + 288, 256, 0, stream>>>(F, D, qw, Fbf, Dbf, Dt2);
    k_main<<<dim3(NCHUNK, 2), 256, 0, stream>>>(Fbf, Dbf, Dt2, part);
    k_reduce<<<576, 256, 0, stream>>>(part, (float*)d_out);
}